// Round 1
// baseline (870.910 us; speedup 1.0000x reference)
//
#include <hip/hip_runtime.h>
#include <hip/hip_bf16.h>

#define DIV_UP(a,b) (((a)+(b)-1)/(b))

// ---------------- preprocessing: degree, dinv, CSR-by-dst ----------------

__global__ __launch_bounds__(256) void k_count(const int* __restrict__ dst, int* __restrict__ counts, int E){
  int e = blockIdx.x*256 + threadIdx.x;
  if (e < E) atomicAdd(&counts[dst[e]], 1);
}

__global__ __launch_bounds__(256) void k_dinv(const int* __restrict__ counts, float* __restrict__ dinv, int N){
  int n = blockIdx.x*256 + threadIdx.x;
  if (n < N) dinv[n] = rsqrtf((float)(counts[n] + 1));  // +1 = self-loop
}

__global__ __launch_bounds__(1024) void k_scan1(const int* __restrict__ counts, int* __restrict__ rowptr,
                                                int* __restrict__ bsum, int N){
  __shared__ int s[1024];
  int t = threadIdx.x, g = blockIdx.x*1024 + t;
  int v = (g < N) ? counts[g] : 0;
  s[t] = v; __syncthreads();
  for (int off = 1; off < 1024; off <<= 1){
    int u = (t >= off) ? s[t-off] : 0; __syncthreads();
    s[t] += u; __syncthreads();
  }
  if (g < N) rowptr[g] = s[t] - v;           // block-local exclusive scan
  if (t == 1023) bsum[blockIdx.x] = s[1023];
}

__global__ __launch_bounds__(128) void k_scan2(const int* __restrict__ bsum, int* __restrict__ boff,
                                               int nb, int* __restrict__ rowptr, int N){
  __shared__ int s[128];
  int t = threadIdx.x;
  int v = (t < nb) ? bsum[t] : 0;
  s[t] = v; __syncthreads();
  for (int off = 1; off < 128; off <<= 1){
    int u = (t >= off) ? s[t-off] : 0; __syncthreads();
    s[t] += u; __syncthreads();
  }
  if (t < nb) boff[t] = s[t] - v;            // exclusive over block sums
  if (t == 127) rowptr[N] = s[127];          // total = E
}

__global__ __launch_bounds__(1024) void k_scan3(int* __restrict__ rowptr, const int* __restrict__ boff, int N){
  int g = blockIdx.x*1024 + threadIdx.x;
  if (g < N) rowptr[g] += boff[blockIdx.x];
}

__global__ __launch_bounds__(256) void k_fill(const int* __restrict__ src, const int* __restrict__ dst,
                                              const int* __restrict__ rowptr, int* __restrict__ fill,
                                              int* __restrict__ csr, int E){
  int e = blockIdx.x*256 + threadIdx.x;
  if (e < E){
    int d = dst[e];
    int pos = rowptr[d] + atomicAdd(&fill[d], 1);
    csr[pos] = src[e];
  }
}

// ---------------- p0 = dinv * x  (64-wide) ----------------
__global__ __launch_bounds__(256) void k_scale(const float* __restrict__ x, const float* __restrict__ dinv,
                                               float* __restrict__ out, int total){
  int i = blockIdx.x*256 + threadIdx.x;
  int idx = i*4;
  if (idx < total){
    int row = idx >> 6;                      // F=64
    float d = dinv[row];
    float4 v = *(const float4*)(x + idx);
    v.x *= d; v.y *= d; v.z *= d; v.w *= d;
    *(float4*)(out + idx) = v;
  }
}

// ---------------- GEMM: out[N,128] = H[N,FIN] @ W[FIN,128], optional dinv-scale / bias+relu ----------------
// block = 64 rows x 128 cols, 256 threads, thread = 4 rows x (4+4) cols, k chunked by 32 via LDS.
template<int FIN>
__global__ __launch_bounds__(256) void k_gemm(const float* __restrict__ H, const float* __restrict__ W,
                                              const float* __restrict__ bias, const float* __restrict__ dinv,
                                              float* __restrict__ out, int N, int relu){
  constexpr int KC = 32;
  __shared__ float Ws[KC][128];
  __shared__ float Hs[64][KC + 4];
  const int tid = threadIdx.x;
  const int rg = tid >> 4, cg = tid & 15;    // rows 4rg..4rg+3, cols {4cg..4cg+3, 64+4cg..64+4cg+3}
  const int row0 = blockIdx.x * 64;

  float acc[4][8];
  #pragma unroll
  for (int i = 0; i < 4; ++i)
    #pragma unroll
    for (int j = 0; j < 8; ++j) acc[i][j] = 0.f;

  const int hr = tid >> 2;                   // staging: row 0..63
  const int hc = (tid & 3) * 8;              // staging: col 0,8,16,24
  int hrow = row0 + hr; if (hrow > N-1) hrow = N-1;

  for (int k0 = 0; k0 < FIN; k0 += KC){
    #pragma unroll
    for (int it = 0; it < 4; ++it){          // stage 32x128 W chunk
      int idx = it*1024 + tid*4;
      int kk = idx >> 7, c = idx & 127;
      *(float4*)&Ws[kk][c] = *(const float4*)(W + (size_t)(k0+kk)*128 + c);
    }
    {                                        // stage 64x32 H chunk
      const float* hp = H + (size_t)hrow*FIN + k0 + hc;
      float4 v0 = *(const float4*)hp;
      float4 v1 = *(const float4*)(hp + 4);
      *(float4*)&Hs[hr][hc]     = v0;
      *(float4*)&Hs[hr][hc + 4] = v1;
    }
    __syncthreads();
    #pragma unroll
    for (int kk = 0; kk < KC; kk += 4){
      float4 a[4];
      #pragma unroll
      for (int i = 0; i < 4; ++i) a[i] = *(const float4*)&Hs[4*rg + i][kk];
      #pragma unroll
      for (int j = 0; j < 4; ++j){
        float4 w0 = *(const float4*)&Ws[kk+j][4*cg];
        float4 w1 = *(const float4*)&Ws[kk+j][64 + 4*cg];
        #pragma unroll
        for (int i = 0; i < 4; ++i){
          float av = ((const float*)&a[i])[j];
          acc[i][0] += av*w0.x; acc[i][1] += av*w0.y; acc[i][2] += av*w0.z; acc[i][3] += av*w0.w;
          acc[i][4] += av*w1.x; acc[i][5] += av*w1.y; acc[i][6] += av*w1.z; acc[i][7] += av*w1.w;
        }
      }
    }
    __syncthreads();
  }

  float blo[4] = {0,0,0,0}, bhi[4] = {0,0,0,0};
  if (bias){
    #pragma unroll
    for (int j = 0; j < 4; ++j){ blo[j] = bias[4*cg + j]; bhi[j] = bias[64 + 4*cg + j]; }
  }
  #pragma unroll
  for (int i = 0; i < 4; ++i){
    int r = row0 + 4*rg + i;
    if (r < N){
      float sc = dinv ? dinv[r] : 1.f;
      float o[8];
      #pragma unroll
      for (int j = 0; j < 8; ++j) o[j] = acc[i][j] * sc;
      if (bias){
        #pragma unroll
        for (int j = 0; j < 4; ++j){ o[j] += blo[j]; o[4+j] += bhi[j]; }
      }
      if (relu){
        #pragma unroll
        for (int j = 0; j < 8; ++j) o[j] = fmaxf(o[j], 0.f);
      }
      float4 u0 = {o[0],o[1],o[2],o[3]}, u1 = {o[4],o[5],o[6],o[7]};
      *(float4*)(out + (size_t)r*128 + 4*cg)      = u0;
      *(float4*)(out + (size_t)r*128 + 64 + 4*cg) = u1;
    }
  }
}

// ---------------- CSR aggregation: out[n] = relu?(dinv[n]*(sum_e p[src]+p[n]) + bias) ----------------
template<int F>
__global__ __launch_bounds__(256) void k_agg(const float* __restrict__ p, const int* __restrict__ rowptr,
                                             const int* __restrict__ csr, const float* __restrict__ dinv,
                                             const float* __restrict__ bias, float* __restrict__ out,
                                             int N, int relu){
  constexpr int LPN = F/4;                   // lanes per node (float4 per lane)
  const int tid = threadIdx.x;
  const int node = blockIdx.x * (256/LPN) + tid / LPN;
  if (node >= N) return;
  const int c = (tid % LPN) * 4;
  const float* pc = p + c;
  int e = rowptr[node], end = rowptr[node+1];
  float4 s = *(const float4*)(p + (size_t)node*F + c);   // self-loop term
  float ax = s.x, ay = s.y, az = s.z, aw = s.w;
  for (; e + 4 <= end; e += 4){
    int s0 = csr[e], s1 = csr[e+1], s2 = csr[e+2], s3 = csr[e+3];
    float4 v0 = *(const float4*)(pc + (size_t)s0*F);
    float4 v1 = *(const float4*)(pc + (size_t)s1*F);
    float4 v2 = *(const float4*)(pc + (size_t)s2*F);
    float4 v3 = *(const float4*)(pc + (size_t)s3*F);
    ax += v0.x+v1.x+v2.x+v3.x; ay += v0.y+v1.y+v2.y+v3.y;
    az += v0.z+v1.z+v2.z+v3.z; aw += v0.w+v1.w+v2.w+v3.w;
  }
  for (; e < end; ++e){
    float4 v = *(const float4*)(pc + (size_t)csr[e]*F);
    ax += v.x; ay += v.y; az += v.z; aw += v.w;
  }
  float d = dinv[node];
  ax *= d; ay *= d; az *= d; aw *= d;
  if (bias){ ax += bias[c]; ay += bias[c+1]; az += bias[c+2]; aw += bias[c+3]; }
  if (relu){ ax = fmaxf(ax,0.f); ay = fmaxf(ay,0.f); az = fmaxf(az,0.f); aw = fmaxf(aw,0.f); }
  float4 o = {ax, ay, az, aw};
  *(float4*)(out + (size_t)node*F + c) = o;
}

// ---------------- final projection: p5[n] = dinv[n] * dot(h[n], W3) ----------------
__global__ __launch_bounds__(256) void k_dot(const float* __restrict__ h, const float* __restrict__ W3,
                                             const float* __restrict__ dinv, float* __restrict__ p5, int N){
  int tid = threadIdx.x;
  int row = blockIdx.x*16 + (tid >> 4);
  int l = tid & 15;
  if (row >= N) return;
  const float* hp = h + (size_t)row*128 + l*8;
  float4 h0 = *(const float4*)hp, h1 = *(const float4*)(hp + 4);
  const float* wp = W3 + l*8;
  float4 w0 = *(const float4*)wp, w1 = *(const float4*)(wp + 4);
  float s = h0.x*w0.x + h0.y*w0.y + h0.z*w0.z + h0.w*w0.w
          + h1.x*w1.x + h1.y*w1.y + h1.z*w1.z + h1.w*w1.w;
  #pragma unroll
  for (int m = 8; m >= 1; m >>= 1) s += __shfl_xor(s, m, 16);
  if (l == 0) p5[row] = dinv[row] * s;
}

// ---------------- final scalar aggregation ----------------
__global__ __launch_bounds__(256) void k_agg1(const float* __restrict__ p5, const int* __restrict__ rowptr,
                                              const int* __restrict__ csr, const float* __restrict__ dinv,
                                              const float* __restrict__ b3, float* __restrict__ out, int N){
  int n = blockIdx.x*256 + threadIdx.x;
  if (n >= N) return;
  int e = rowptr[n], end = rowptr[n+1];
  float acc = p5[n];
  for (; e + 4 <= end; e += 4)
    acc += p5[csr[e]] + p5[csr[e+1]] + p5[csr[e+2]] + p5[csr[e+3]];
  for (; e < end; ++e) acc += p5[csr[e]];
  out[n] = dinv[n]*acc + b3[0];
}

extern "C" void kernel_launch(void* const* d_in, const int* in_sizes, int n_in,
                              void* d_out, int out_size, void* d_ws, size_t ws_size,
                              hipStream_t stream){
  const float* x  = (const float*)d_in[0];
  const int*   ei = (const int*)  d_in[1];
  const float* W1 = (const float*)d_in[2];
  const float* b1 = (const float*)d_in[3];
  const float* W2 = (const float*)d_in[4];
  const float* b2 = (const float*)d_in[5];
  const float* W3 = (const float*)d_in[6];
  const float* b3 = (const float*)d_in[7];
  float* out = (float*)d_out;

  const int N = in_sizes[0] / 64;
  const int E = in_sizes[1] / 2;
  const int L = in_sizes[4] / (128*128);
  const int* src = ei;
  const int* dst = ei + E;

  char* ws = (char*)d_ws;
  size_t off = 0;
  auto alloc = [&](size_t bytes){ void* p = ws + off; off += (bytes + 255) & ~(size_t)255; return p; };
  int*   counts = (int*)  alloc((size_t)N*4);
  int*   fillc  = (int*)  alloc((size_t)N*4);
  int*   rowptr = (int*)  alloc((size_t)(N+1)*4);
  int*   bsum   = (int*)  alloc(128*4);
  int*   boff   = (int*)  alloc(128*4);
  float* dinv   = (float*)alloc((size_t)N*4);
  int*   csr    = (int*)  alloc((size_t)E*4);
  float* bufA   = (float*)alloc((size_t)N*128*4);
  float* bufB   = (float*)alloc((size_t)N*128*4);
  (void)ws_size; (void)n_in; (void)out_size;

  hipMemsetAsync(counts, 0, (size_t)N*4, stream);
  hipMemsetAsync(fillc,  0, (size_t)N*4, stream);

  k_count<<<DIV_UP(E,256),256,0,stream>>>(dst, counts, E);
  k_dinv <<<DIV_UP(N,256),256,0,stream>>>(counts, dinv, N);
  int nb = DIV_UP(N,1024);
  k_scan1<<<nb,1024,0,stream>>>(counts, rowptr, bsum, N);
  k_scan2<<<1,128,0,stream>>>(bsum, boff, nb, rowptr, N);
  k_scan3<<<nb,1024,0,stream>>>(rowptr, boff, N);
  k_fill <<<DIV_UP(E,256),256,0,stream>>>(src, dst, rowptr, fillc, csr, E);

  // layer 1 (agg-first since aggregation is linear; 64-wide halves gather traffic)
  k_scale<<<DIV_UP(N*16,256),256,0,stream>>>(x, dinv, bufA, N*64);
  k_agg<64><<<DIV_UP(N,16),256,0,stream>>>(bufA, rowptr, csr, dinv, nullptr, bufB, N, 0);
  k_gemm<64><<<DIV_UP(N,64),256,0,stream>>>(bufB, W1, b1, nullptr, bufA, N, 1);

  // layers 2..4
  for (int i = 0; i < L; ++i){
    k_gemm<128><<<DIV_UP(N,64),256,0,stream>>>(bufA, W2 + (size_t)i*128*128, nullptr, dinv, bufB, N, 0);
    k_agg<128><<<DIV_UP(N,8),256,0,stream>>>(bufB, rowptr, csr, dinv, b2 + (size_t)i*128, bufA, N, 1);
  }

  // output layer (project to 1 dim BEFORE aggregating: scalar gather)
  k_dot <<<DIV_UP(N,16),256,0,stream>>>(bufA, W3, dinv, bufB, N);
  k_agg1<<<DIV_UP(N,256),256,0,stream>>>(bufB, rowptr, csr, dinv, b3, out, N);
}